// Round 18
// baseline (112.384 us; speedup 1.0000x reference)
//
#include <hip/hip_runtime.h>
#include <hip/hip_bf16.h>
#include <math.h>

// Problem constants
#define NB     4
#define NTOK   4096
#define IND    1024
#define LAT    128
#define MTOT   (NB*NTOK)
#define L2E    1.4426950408889634f
#define SC2    0.022542110013890053f   // (1/64) * log2(e), folded into Qp

typedef short bf16x8 __attribute__((ext_vector_type(8)));
typedef float f32x4  __attribute__((ext_vector_type(4)));
typedef float f32x16 __attribute__((ext_vector_type(16)));

__device__ __forceinline__ unsigned short f2bf(float x) {
    union { float f; unsigned int u; } v; v.f = x;
    unsigned int r = v.u + 0x7FFFu + ((v.u >> 16) & 1u);  // RNE
    return (unsigned short)(r >> 16);
}
__device__ __forceinline__ float bf2f(unsigned short b) {
    union { unsigned int u; float f; } v; v.u = ((unsigned int)b) << 16;
    return v.f;
}
__device__ __forceinline__ unsigned cvtpk(float lo, float hi) {
    unsigned r;
    asm("v_cvt_pk_bf16_f32 %0, %1, %2" : "=v"(r) : "v"(lo), "v"(hi));
    return r;
}
// v_permlane32_swap_b32: x.hi32lanes <-> y.lo32lanes
__device__ __forceinline__ void permswap(unsigned &x, unsigned &y) {
    asm volatile("v_permlane32_swap_b32 %0, %1" : "+v"(x), "+v"(y));
}
// async global->LDS, 16B/lane. dest = wave-uniform base + lane*16 (HW).
__device__ __forceinline__ void gld16(const void* g, void* l) {
    __builtin_amdgcn_global_load_lds(
        (const __attribute__((address_space(1))) void*)g,
        (__attribute__((address_space(3))) void*)l, 16, 0, 0);
}

// ===========================================================================
// fuse_w (proven)
// ===========================================================================
__global__ __launch_bounds__(256) void fuse_w(const float* __restrict__ Wq,
                                              const float* __restrict__ Wk,
                                              const float* __restrict__ bk,
                                              const float* __restrict__ bq,
                                              unsigned short* __restrict__ Wcomb,
                                              float* __restrict__ bqk) {
    const int o = blockIdx.y;                       // 0..127
    const int i = blockIdx.x * 256 + threadIdx.x;   // 0..1023
    Wcomb[(size_t)o * IND + i] = f2bf(Wk[(size_t)o * IND + i]);
    float acc = 0.f;
    #pragma unroll 8
    for (int l = 0; l < 128; ++l)
        acc = fmaf(Wq[o * 128 + l], Wk[(size_t)l * IND + i], acc);
    Wcomb[(size_t)(128 + o) * IND + i] = f2bf(acc * SC2);
    if (blockIdx.x == 0 && threadIdx.x == 0) {
        float b = bq[o];
        for (int l = 0; l < 128; ++l) b = fmaf(Wq[o * 128 + l], bk[l], b);
        bqk[o] = b * SC2;
    }
}

// ===========================================================================
// proj_all3: fused projections, BM=64 (R17 proven) + BK=128: 8 k-steps
// instead of 16 -> half the barrier events again (R17's confirmed lever).
// LDS = A [64][128]bf16 16KB + B [<=256][128]bf16 64KB = 80KB -> 2 blocks/CU.
// All rows 256B: uniform 16-slot swizzle (row&15)<<4 (attn7-proven).
// blocks 0..255: [Kp|Qp] = Q @ [Wk|Wqk]^T + bias ; 256..511: VpT.
// ===========================================================================
__global__ __launch_bounds__(256, 2) void proj_all3(const float* __restrict__ Q,
                                                    const unsigned short* __restrict__ Wcomb,
                                                    const float* __restrict__ bk,
                                                    const float* __restrict__ bqk,
                                                    unsigned short* __restrict__ Kp,
                                                    unsigned short* __restrict__ Qp,
                                                    const float* __restrict__ V,
                                                    const float* __restrict__ Wv,
                                                    const float* __restrict__ bv,
                                                    unsigned short* __restrict__ VpT) {
    __shared__ __align__(16) char lds[16384 + 65536];   // A [64][128]bf16, B [<=256][128]bf16
    const int t = threadIdx.x, l = t & 63, w = t >> 6;
    const int lrow = l & 15, lhi = l >> 4;
    const int wr = (w >> 1) * 32;

    if (blockIdx.x < 256) {
        // ------------------ qk half ------------------
        const int br = blockIdx.x;
        const int wc = (w & 1) * 128;
        f32x4 acc[2][8] = {};

        float4 aR[8];     // A: 64x128 f32 = 2048 float4 / 256thr = 8
        bf16x8 bR[16];    // B: 256x128 bf16 = 4096 x16B / 256thr = 16
        #pragma unroll
        for (int j = 0; j < 8; ++j) {
            int c = t + j * 256, row = c >> 5, ch = c & 31;
            aR[j] = *(const float4*)&Q[(size_t)(br * 64 + row) * IND + ch * 4];
        }
        #pragma unroll
        for (int j = 0; j < 16; ++j) {
            int c = t + j * 256, row = c >> 4, ch = c & 15;
            bR[j] = *(const bf16x8*)&Wcomb[(size_t)row * IND + ch * 8];
        }

        for (int k0 = 0; k0 < IND; k0 += 128) {
            #pragma unroll
            for (int j = 0; j < 8; ++j) {
                int c = t + j * 256, row = c >> 5, ch = c & 31;
                union { unsigned short s[4]; unsigned long long q; } pk;
                pk.s[0] = f2bf(aR[j].x); pk.s[1] = f2bf(aR[j].y);
                pk.s[2] = f2bf(aR[j].z); pk.s[3] = f2bf(aR[j].w);
                *(unsigned long long*)(lds + ((row * 256 + ch * 8) ^ ((row & 15) << 4))) = pk.q;
            }
            #pragma unroll
            for (int j = 0; j < 16; ++j) {
                int c = t + j * 256, row = c >> 4, ch = c & 15;
                *(bf16x8*)(lds + 16384 + ((row * 256 + ch * 16) ^ ((row & 15) << 4))) = bR[j];
            }
            if (k0 + 128 < IND) {
                #pragma unroll
                for (int j = 0; j < 8; ++j) {
                    int c = t + j * 256, row = c >> 5, ch = c & 31;
                    aR[j] = *(const float4*)&Q[(size_t)(br * 64 + row) * IND + k0 + 128 + ch * 4];
                }
                #pragma unroll
                for (int j = 0; j < 16; ++j) {
                    int c = t + j * 256, row = c >> 4, ch = c & 15;
                    bR[j] = *(const bf16x8*)&Wcomb[(size_t)row * IND + k0 + 128 + ch * 8];
                }
            }
            __syncthreads();

            #pragma unroll
            for (int kk = 0; kk < 4; ++kk) {
                bf16x8 a[2];
                #pragma unroll
                for (int m = 0; m < 2; ++m) {
                    const int arow = wr + m * 16 + lrow;
                    a[m] = *(const bf16x8*)(lds +
                        ((arow * 256 + kk * 64 + lhi * 16) ^ ((arow & 15) << 4)));
                }
                #pragma unroll
                for (int n = 0; n < 8; ++n) {
                    const int brow = wc + n * 16 + lrow;
                    bf16x8 b = *(const bf16x8*)(lds + 16384 +
                        ((brow * 256 + kk * 64 + lhi * 16) ^ ((brow & 15) << 4)));
                    #pragma unroll
                    for (int m = 0; m < 2; ++m)
                        acc[m][n] = __builtin_amdgcn_mfma_f32_16x16x32_bf16(a[m], b, acc[m][n], 0, 0, 0);
                }
            }
            __syncthreads();
        }

        #pragma unroll
        for (int m = 0; m < 2; ++m) {
            const int row0 = br * 64 + wr + m * 16 + lhi * 4;
            unsigned short* out = (wc == 0) ? Kp : Qp;
            const float* bias = (wc == 0) ? bk : bqk;
            #pragma unroll
            for (int n = 0; n < 8; ++n) {
                int col = n * 16 + lrow;
                float bv_ = bias[col];
                #pragma unroll
                for (int r = 0; r < 4; ++r)
                    out[(size_t)(row0 + r) * LAT + col] = f2bf(acc[m][n][r] + bv_);
            }
        }
    } else {
        // ------------------ v half ------------------
        const int br = blockIdx.x - 256;
        const int wc = (w & 1) * 64;
        f32x4 acc[2][4] = {};

        float4 aR[8], bR[16];   // B: 128x128 f32 = 4096 float4 / 256thr = 16
        #pragma unroll
        for (int j = 0; j < 8; ++j) {
            int c = t + j * 256, row = c >> 5, ch = c & 31;
            aR[j] = *(const float4*)&V[(size_t)(br * 64 + row) * IND + ch * 4];
        }
        #pragma unroll
        for (int j = 0; j < 16; ++j) {
            int c = t + j * 256, row = c >> 5, ch = c & 31;
            bR[j] = *(const float4*)&Wv[(size_t)row * IND + ch * 4];
        }

        for (int k0 = 0; k0 < IND; k0 += 128) {
            #pragma unroll
            for (int j = 0; j < 8; ++j) {
                int c = t + j * 256, row = c >> 5, ch = c & 31;
                union { unsigned short s[4]; unsigned long long q; } pk;
                pk.s[0] = f2bf(aR[j].x); pk.s[1] = f2bf(aR[j].y);
                pk.s[2] = f2bf(aR[j].z); pk.s[3] = f2bf(aR[j].w);
                *(unsigned long long*)(lds + ((row * 256 + ch * 8) ^ ((row & 15) << 4))) = pk.q;
            }
            #pragma unroll
            for (int j = 0; j < 16; ++j) {
                int c = t + j * 256, row = c >> 5, ch = c & 31;
                union { unsigned short s[4]; unsigned long long q; } pk;
                pk.s[0] = f2bf(bR[j].x); pk.s[1] = f2bf(bR[j].y);
                pk.s[2] = f2bf(bR[j].z); pk.s[3] = f2bf(bR[j].w);
                *(unsigned long long*)(lds + 16384 + ((row * 256 + ch * 8) ^ ((row & 15) << 4))) = pk.q;
            }
            if (k0 + 128 < IND) {
                #pragma unroll
                for (int j = 0; j < 8; ++j) {
                    int c = t + j * 256, row = c >> 5, ch = c & 31;
                    aR[j] = *(const float4*)&V[(size_t)(br * 64 + row) * IND + k0 + 128 + ch * 4];
                }
                #pragma unroll
                for (int j = 0; j < 16; ++j) {
                    int c = t + j * 256, row = c >> 5, ch = c & 31;
                    bR[j] = *(const float4*)&Wv[(size_t)row * IND + k0 + 128 + ch * 4];
                }
            }
            __syncthreads();

            #pragma unroll
            for (int kk = 0; kk < 4; ++kk) {
                bf16x8 a[2];
                #pragma unroll
                for (int m = 0; m < 2; ++m) {
                    const int arow = wr + m * 16 + lrow;
                    a[m] = *(const bf16x8*)(lds +
                        ((arow * 256 + kk * 64 + lhi * 16) ^ ((arow & 15) << 4)));
                }
                #pragma unroll
                for (int n = 0; n < 4; ++n) {
                    const int brow = wc + n * 16 + lrow;
                    bf16x8 b = *(const bf16x8*)(lds + 16384 +
                        ((brow * 256 + kk * 64 + lhi * 16) ^ ((brow & 15) << 4)));
                    #pragma unroll
                    for (int m = 0; m < 2; ++m)
                        acc[m][n] = __builtin_amdgcn_mfma_f32_16x16x32_bf16(a[m], b, acc[m][n], 0, 0, 0);
                }
            }
            __syncthreads();
        }

        #pragma unroll
        for (int m = 0; m < 2; ++m) {
            const int row0 = br * 64 + wr + m * 16 + lhi * 4;
            const int batch = row0 >> 12, tok = row0 & 4095;
            #pragma unroll
            for (int n = 0; n < 4; ++n) {
                int col = wc + n * 16 + lrow;
                float bv_ = bv[col];
                union { unsigned short s[4]; unsigned long long q; } pk;
                #pragma unroll
                for (int r = 0; r < 4; ++r) pk.s[r] = f2bf(acc[m][n][r] + bv_);
                *(unsigned long long*)&VpT[(size_t)batch * (LAT * NTOK) + (size_t)col * NTOK + tok] = pk.q;
            }
        }
    }
}

// ===========================================================================
// attn7<NSPLIT>: KVBLK=64, 4 waves x 32 q, 2-buffer gld_lds (pre-swizzled
// source), static max. Proven 54.4 us. Unchanged.
// ===========================================================================
template<int NSPLIT>
__global__ __launch_bounds__(256, 2) void attn7(const unsigned short* __restrict__ Qp,
                                                const unsigned short* __restrict__ Kp,
                                                const unsigned short* __restrict__ VpT,
                                                unsigned short* __restrict__ Opart,
                                                float* __restrict__ lsum,
                                                float* __restrict__ Y) {
    __shared__ __align__(16) char ldsK[2][16384];   // K [64 k][128 d] bf16
    __shared__ __align__(16) char ldsV[2][16384];   // VT [128 d][64 k] bf16
    const int t = threadIdx.x, l = t & 63, w = t >> 6;
    const int lane31 = l & 31, hi = l >> 5;

    int qt, b, ck;
    if constexpr (NSPLIT > 1) {
        int x = blockIdx.x;
        int glo = x & 7, rest = x >> 3;
        qt = rest & 31;
        int g = glo + 8 * (rest >> 5);   // 0 .. NB*NSPLIT-1
        b = g / NSPLIT; ck = g % NSPLIT;
    } else {
        qt = blockIdx.x & 31; b = blockIdx.x >> 5; ck = 0;
    }
    const size_t base  = (size_t)b * ((size_t)NTOK * LAT);
    const size_t vbase = (size_t)b * ((size_t)LAT * NTOK);
    const int wq = qt * 128 + w * 32;
    const int k_base = ck * (NTOK / NSPLIT);
    const int kts = (NTOK / NSPLIT) / 64;

    const int kc_row = t >> 4, kc_ch = t & 15;   // K: c=t+j*256 -> row=kc_row+j*16
    const int vc_row = t >> 3, vc_ch = t & 7;    // V: c=t+j*256 -> row=vc_row+j*32

    auto STAGE = [&](int bi, int k_lo) {
        #pragma unroll
        for (int j = 0; j < 4; ++j) {
            int row = kc_row + j * 16;
            gld16(&Kp[base + (size_t)(k_lo + row) * LAT + (kc_ch ^ (row & 15)) * 8],
                  &ldsK[bi][j * 4096 + w * 1024]);
        }
        #pragma unroll
        for (int j = 0; j < 4; ++j) {
            int row = vc_row + j * 32;
            gld16(&VpT[vbase + (size_t)row * NTOK + k_lo + (vc_ch ^ (row & 7)) * 8],
                  &ldsV[bi][j * 4096 + w * 1024]);
        }
    };

    bf16x8 qf[8];
    {
        const size_t qrow = base + (size_t)(wq + lane31) * LAT;
        #pragma unroll
        for (int ds = 0; ds < 8; ++ds)
            qf[ds] = *(const bf16x8*)&Qp[qrow + ds * 16 + hi * 8];
    }

    f32x16 OA[4] = {};
    float lrun = 0.f;

    int buf = 0;
    STAGE(0, k_base);
    asm volatile("s_waitcnt vmcnt(0)" ::: "memory");
    __syncthreads();

    for (int kt = 0; kt < kts; ++kt) {
        if (kt + 1 < kts) STAGE(buf ^ 1, k_base + (kt + 1) * 64);
        const char* lK = ldsK[buf];
        const char* lV = ldsV[buf];

        f32x16 SA[2];
        __builtin_amdgcn_s_setprio(1);
        #pragma unroll
        for (int kb = 0; kb < 2; ++kb) {
            f32x16 s = {};
            const int kr = kb * 32 + lane31;
            const int ksw = (kr & 15) << 4;
            #pragma unroll
            for (int ds = 0; ds < 8; ++ds) {
                bf16x8 kf = *(const bf16x8*)(lK + ((kr * 256 + ds * 32 + hi * 16) ^ ksw));
                s = __builtin_amdgcn_mfma_f32_32x32x16_bf16(kf, qf[ds], s, 0, 0, 0);
            }
            SA[kb] = s;
        }
        __builtin_amdgcn_s_setprio(0);

        #pragma unroll
        for (int kb = 0; kb < 2; ++kb) {
            float p[16];
            #pragma unroll
            for (int r = 0; r < 16; ++r) {
                p[r] = exp2f(SA[kb][r]);
                lrun += p[r];
            }
            unsigned a0 = cvtpk(p[0], p[1]),  a1 = cvtpk(p[2], p[3]);
            unsigned a2 = cvtpk(p[4], p[5]),  a3 = cvtpk(p[6], p[7]);
            permswap(a0, a2); permswap(a1, a3);
            unsigned b0 = cvtpk(p[8], p[9]),   b1 = cvtpk(p[10], p[11]);
            unsigned b2 = cvtpk(p[12], p[13]), b3 = cvtpk(p[14], p[15]);
            permswap(b0, b2); permswap(b1, b3);
            union { unsigned u[4]; bf16x8 v; } f0 = {{a0, a1, a2, a3}};
            union { unsigned u[4]; bf16x8 v; } f1 = {{b0, b1, b2, b3}};

            __builtin_amdgcn_s_setprio(1);
            #pragma unroll
            for (int db = 0; db < 4; ++db) {
                const int d = db * 32 + lane31;
                const int vsw = (d & 7) << 4;
                bf16x8 vfA = *(const bf16x8*)(lV + ((d * 128 + (kb * 2 + 0) * 32 + hi * 16) ^ vsw));
                OA[db] = __builtin_amdgcn_mfma_f32_32x32x16_bf16(vfA, f0.v, OA[db], 0, 0, 0);
                bf16x8 vfB = *(const bf16x8*)(lV + ((d * 128 + (kb * 2 + 1) * 32 + hi * 16) ^ vsw));
                OA[db] = __builtin_amdgcn_mfma_f32_32x32x16_bf16(vfB, f1.v, OA[db], 0, 0, 0);
            }
            __builtin_amdgcn_s_setprio(0);
        }

        asm volatile("s_waitcnt vmcnt(0)" ::: "memory");
        __syncthreads();
        buf ^= 1;
    }

    const float ltot = lrun + __shfl_xor(lrun, 32);

    if constexpr (NSPLIT == 1) {
        const float inv = 1.0f / ltot;
        float* dst = &Y[base + (size_t)(wq + lane31) * LAT];
        #pragma unroll
        for (int db = 0; db < 4; ++db)
            #pragma unroll
            for (int g = 0; g < 4; ++g) {
                f32x4 v;
                #pragma unroll
                for (int j = 0; j < 4; ++j) v[j] = OA[db][4 * g + j] * inv;
                *(f32x4*)&dst[db * 32 + 8 * g + 4 * hi] = v;
            }
    } else {
        const size_t prow = (size_t)ck * MTOT + (size_t)b * NTOK + wq + lane31;
        unsigned short* dst = &Opart[prow * LAT];
        #pragma unroll
        for (int db = 0; db < 4; ++db)
            #pragma unroll
            for (int g = 0; g < 4; ++g) {
                union { unsigned short s[4]; unsigned long long q; } pk;
                #pragma unroll
                for (int j = 0; j < 4; ++j) pk.s[j] = f2bf(OA[db][4 * g + j]);
                *(unsigned long long*)&dst[db * 32 + 8 * g + 4 * hi] = pk.q;
            }
        if (l < 32) lsum[prow] = ltot;
    }
}

// ===========================================================================
// merge3<S>: Y = (sum_c O_c) / (sum_c l_c).  (proven round 7)
// ===========================================================================
template<int S>
__global__ __launch_bounds__(256) void merge3(const unsigned short* __restrict__ Opart,
                                              const float* __restrict__ lsum,
                                              float* __restrict__ Y) {
    const int idx = blockIdx.x * 256 + threadIdx.x;
    const int row = idx >> 4, cc = (idx & 15) * 8;
    float L = 0.f;
    #pragma unroll
    for (int c = 0; c < S; ++c) L += lsum[(size_t)c * MTOT + row];
    float acc[8] = {};
    #pragma unroll
    for (int c = 0; c < S; ++c) {
        bf16x8 v = *(const bf16x8*)&Opart[((size_t)c * MTOT + row) * LAT + cc];
        #pragma unroll
        for (int j = 0; j < 8; ++j)
            acc[j] += bf2f((unsigned short)v[j]);
    }
    const float inv = 1.f / L;
    f32x4 o0, o1;
    #pragma unroll
    for (int j = 0; j < 4; ++j) { o0[j] = acc[j] * inv; o1[j] = acc[4 + j] * inv; }
    *(f32x4*)&Y[(size_t)row * LAT + cc] = o0;
    *(f32x4*)&Y[(size_t)row * LAT + cc + 4] = o1;
}

// ===========================================================================
extern "C" void kernel_launch(void* const* d_in, const int* in_sizes, int n_in,
                              void* d_out, int out_size, void* d_ws, size_t ws_size,
                              hipStream_t stream) {
    const float* Q  = (const float*)d_in[0];
    // d_in[1] (K) ignored by reference
    const float* V  = (const float*)d_in[2];
    const float* Wk = (const float*)d_in[3];
    const float* bk = (const float*)d_in[4];
    const float* Wq = (const float*)d_in[5];
    const float* bq = (const float*)d_in[6];
    const float* Wv = (const float*)d_in[7];
    const float* bv = (const float*)d_in[8];
    float* Y = (float*)d_out;

    char* ws = (char*)d_ws;
    unsigned short* Kp    = (unsigned short*)(ws);                 // 4 MB
    unsigned short* Qp    = (unsigned short*)(ws + (4 << 20));     // 4 MB
    unsigned short* VpT   = (unsigned short*)(ws + (8 << 20));     // 4 MB
    unsigned short* Wcomb = (unsigned short*)(ws + (12 << 20));    // 512 KB
    float*          bqk   = (float*)         (ws + 13107200);      // 512 B
    float*          lsum  = (float*)         (ws + 13107712);      // <=512 KB
    unsigned short* Opart = (unsigned short*)(ws + 14680064);      // partials
    const size_t need4 = 14680064 + (size_t)4 * MTOT * LAT * 2;    // ~31.5 MB

    fuse_w<<<dim3(4, 128), 256, 0, stream>>>(Wq, Wk, bk, bq, Wcomb, bqk);
    proj_all3<<<dim3(512), 256, 0, stream>>>(Q, Wcomb, bk, bqk, Kp, Qp, V, Wv, bv, VpT);

    if (ws_size >= need4) {
        attn7<4><<<dim3(32 * NB * 4), 256, 0, stream>>>(Qp, Kp, VpT, Opart, lsum, nullptr);
        merge3<4><<<dim3(MTOT * 16 / 256), 256, 0, stream>>>(Opart, lsum, Y);
    } else {
        attn7<1><<<dim3(32 * NB), 256, 0, stream>>>(Qp, Kp, VpT, nullptr, nullptr, Y);
    }
}

// Round 19
// 93.712 us; speedup vs baseline: 1.1992x; 1.1992x over previous
//
#include <hip/hip_runtime.h>
#include <hip/hip_bf16.h>
#include <math.h>

// Problem constants
#define NB     4
#define NTOK   4096
#define IND    1024
#define LAT    128
#define MTOT   (NB*NTOK)
#define L2E    1.4426950408889634f
#define SC2    0.022542110013890053f   // (1/64) * log2(e), folded into Qp

typedef short bf16x8 __attribute__((ext_vector_type(8)));
typedef float f32x4  __attribute__((ext_vector_type(4)));
typedef float f32x16 __attribute__((ext_vector_type(16)));

__device__ __forceinline__ unsigned short f2bf(float x) {
    union { float f; unsigned int u; } v; v.f = x;
    unsigned int r = v.u + 0x7FFFu + ((v.u >> 16) & 1u);  // RNE
    return (unsigned short)(r >> 16);
}
__device__ __forceinline__ float bf2f(unsigned short b) {
    union { unsigned int u; float f; } v; v.u = ((unsigned int)b) << 16;
    return v.f;
}
__device__ __forceinline__ unsigned cvtpk(float lo, float hi) {
    unsigned r;
    asm("v_cvt_pk_bf16_f32 %0, %1, %2" : "=v"(r) : "v"(lo), "v"(hi));
    return r;
}
// v_permlane32_swap_b32: x.hi32lanes <-> y.lo32lanes
__device__ __forceinline__ void permswap(unsigned &x, unsigned &y) {
    asm volatile("v_permlane32_swap_b32 %0, %1" : "+v"(x), "+v"(y));
}
// async global->LDS, 16B/lane. dest = wave-uniform base + lane*16 (HW).
__device__ __forceinline__ void gld16(const void* g, void* l) {
    __builtin_amdgcn_global_load_lds(
        (const __attribute__((address_space(1))) void*)g,
        (__attribute__((address_space(3))) void*)l, 16, 0, 0);
}

// ===========================================================================
// fuse_w (proven)
// ===========================================================================
__global__ __launch_bounds__(256) void fuse_w(const float* __restrict__ Wq,
                                              const float* __restrict__ Wk,
                                              const float* __restrict__ bk,
                                              const float* __restrict__ bq,
                                              unsigned short* __restrict__ Wcomb,
                                              float* __restrict__ bqk) {
    const int o = blockIdx.y;                       // 0..127
    const int i = blockIdx.x * 256 + threadIdx.x;   // 0..1023
    Wcomb[(size_t)o * IND + i] = f2bf(Wk[(size_t)o * IND + i]);
    float acc = 0.f;
    #pragma unroll 8
    for (int l = 0; l < 128; ++l)
        acc = fmaf(Wq[o * 128 + l], Wk[(size_t)l * IND + i], acc);
    Wcomb[(size_t)(128 + o) * IND + i] = f2bf(acc * SC2);
    if (blockIdx.x == 0 && threadIdx.x == 0) {
        float b = bq[o];
        for (int l = 0; l < 128; ++l) b = fmaf(Wq[o * 128 + l], bk[l], b);
        bqk[o] = b * SC2;
    }
}

// ===========================================================================
// proj_all4: R17's proj_all2 (BM=64, BK=64, same staging registers, same
// zero-conflict swizzles) + DOUBLE-BUFFERED LDS -> ONE barrier per k-step
// (vs 2). Per step s: write regs(s+1)->LDS[(s+1)&1]; issue loads(s+2);
// compute from LDS[s&1]; barrier. The written buffer was last read at s-1
// (drained by that step's barrier) -> single barrier is sufficient.
// LDS = 2 x (A 8KB + B 32KB) = 80KB -> exactly 2 blocks/CU.
// blocks 0..255: [Kp|Qp] = Q @ [Wk|Wqk]^T + bias ; 256..511: VpT.
// ===========================================================================
__global__ __launch_bounds__(256, 2) void proj_all4(const float* __restrict__ Q,
                                                    const unsigned short* __restrict__ Wcomb,
                                                    const float* __restrict__ bk,
                                                    const float* __restrict__ bqk,
                                                    unsigned short* __restrict__ Kp,
                                                    unsigned short* __restrict__ Qp,
                                                    const float* __restrict__ V,
                                                    const float* __restrict__ Wv,
                                                    const float* __restrict__ bv,
                                                    unsigned short* __restrict__ VpT) {
    __shared__ __align__(16) char lds[2][40960];   // per buf: A [64][64]bf16 @0, B [<=256][64]bf16 @8192
    const int t = threadIdx.x, l = t & 63, w = t >> 6;
    const int lrow = l & 15, lhi = l >> 4;
    const int wr = (w >> 1) * 32;

    if (blockIdx.x < 256) {
        // ------------------ qk half ------------------
        const int br = blockIdx.x;
        const int wc = (w & 1) * 128;
        f32x4 acc[2][8] = {};

        float4 aR[4];
        bf16x8 bR[8];
        // staging index precompute
        const int a_row = t >> 2, a_ch = t & 3;      // A chunk j: c=t+j*256 -> row=(c>>4), but keep proj_all2 formulas inline
        (void)a_row; (void)a_ch;

        auto LOADT = [&](int k0) {
            #pragma unroll
            for (int j = 0; j < 4; ++j) {
                int c = t + j * 256, row = c >> 4, ch = c & 15;
                aR[j] = *(const float4*)&Q[(size_t)(br * 64 + row) * IND + k0 + ch * 4];
            }
            #pragma unroll
            for (int j = 0; j < 8; ++j) {
                int c = t + j * 256, row = c >> 3, ch = c & 7;
                bR[j] = *(const bf16x8*)&Wcomb[(size_t)row * IND + k0 + ch * 8];
            }
        };
        auto WRITET = [&](int bi) {
            char* L = lds[bi];
            #pragma unroll
            for (int j = 0; j < 4; ++j) {
                int c = t + j * 256, row = c >> 4, ch = c & 15;
                union { unsigned short s[4]; unsigned long long q; } pk;
                pk.s[0] = f2bf(aR[j].x); pk.s[1] = f2bf(aR[j].y);
                pk.s[2] = f2bf(aR[j].z); pk.s[3] = f2bf(aR[j].w);
                *(unsigned long long*)(L + ((row * 128 + ch * 8) ^ ((row & 7) << 4))) = pk.q;
            }
            #pragma unroll
            for (int j = 0; j < 8; ++j) {
                int c = t + j * 256, row = c >> 3, ch = c & 7;
                *(bf16x8*)(L + 8192 + ((row * 128 + ch * 16) ^ ((row & 7) << 4))) = bR[j];
            }
        };

        LOADT(0);
        WRITET(0);
        LOADT(64);
        __syncthreads();

        for (int s = 0; s < 16; ++s) {
            if (s + 1 < 16) WRITET((s + 1) & 1);       // regs hold tile s+1
            if (s + 2 < 16) LOADT((s + 2) * 64);       // fly under compute
            const char* L = lds[s & 1];

            bf16x8 a[2][2];
            #pragma unroll
            for (int m = 0; m < 2; ++m) {
                const int arow = wr + m * 16 + lrow;
                #pragma unroll
                for (int kk = 0; kk < 2; ++kk)
                    a[m][kk] = *(const bf16x8*)(L +
                        ((arow * 128 + kk * 64 + lhi * 16) ^ ((arow & 7) << 4)));
            }
            #pragma unroll
            for (int n = 0; n < 8; ++n) {
                const int brow = wc + n * 16 + lrow;
                #pragma unroll
                for (int kk = 0; kk < 2; ++kk) {
                    bf16x8 b = *(const bf16x8*)(L + 8192 +
                        ((brow * 128 + kk * 64 + lhi * 16) ^ ((brow & 7) << 4)));
                    #pragma unroll
                    for (int m = 0; m < 2; ++m)
                        acc[m][n] = __builtin_amdgcn_mfma_f32_16x16x32_bf16(a[m][kk], b, acc[m][n], 0, 0, 0);
                }
            }
            __syncthreads();
        }

        #pragma unroll
        for (int m = 0; m < 2; ++m) {
            const int row0 = br * 64 + wr + m * 16 + lhi * 4;
            unsigned short* out = (wc == 0) ? Kp : Qp;
            const float* bias = (wc == 0) ? bk : bqk;
            #pragma unroll
            for (int n = 0; n < 8; ++n) {
                int col = n * 16 + lrow;
                float bv_ = bias[col];
                #pragma unroll
                for (int r = 0; r < 4; ++r)
                    out[(size_t)(row0 + r) * LAT + col] = f2bf(acc[m][n][r] + bv_);
            }
        }
    } else {
        // ------------------ v half ------------------
        const int br = blockIdx.x - 256;
        const int wc = (w & 1) * 64;
        f32x4 acc[2][4] = {};

        float4 aR[4], bR[8];
        auto LOADT = [&](int k0) {
            #pragma unroll
            for (int j = 0; j < 4; ++j) {
                int c = t + j * 256, row = c >> 4, ch = c & 15;
                aR[j] = *(const float4*)&V[(size_t)(br * 64 + row) * IND + k0 + ch * 4];
            }
            #pragma unroll
            for (int j = 0; j < 8; ++j) {
                int c = t + j * 256, row = c >> 4, ch = c & 15;
                bR[j] = *(const float4*)&Wv[(size_t)row * IND + k0 + ch * 4];
            }
        };
        auto WRITET = [&](int bi) {
            char* L = lds[bi];
            #pragma unroll
            for (int j = 0; j < 4; ++j) {
                int c = t + j * 256, row = c >> 4, ch = c & 15;
                union { unsigned short s[4]; unsigned long long q; } pk;
                pk.s[0] = f2bf(aR[j].x); pk.s[1] = f2bf(aR[j].y);
                pk.s[2] = f2bf(aR[j].z); pk.s[3] = f2bf(aR[j].w);
                *(unsigned long long*)(L + ((row * 128 + ch * 8) ^ ((row & 7) << 4))) = pk.q;
            }
            #pragma unroll
            for (int j = 0; j < 8; ++j) {
                int c = t + j * 256, row = c >> 4, ch = c & 15;
                union { unsigned short s[4]; unsigned long long q; } pk;
                pk.s[0] = f2bf(bR[j].x); pk.s[1] = f2bf(bR[j].y);
                pk.s[2] = f2bf(bR[j].z); pk.s[3] = f2bf(bR[j].w);
                *(unsigned long long*)(L + 8192 + ((row * 128 + ch * 8) ^ ((row & 7) << 4))) = pk.q;
            }
        };

        LOADT(0);
        WRITET(0);
        LOADT(64);
        __syncthreads();

        for (int s = 0; s < 16; ++s) {
            if (s + 1 < 16) WRITET((s + 1) & 1);
            if (s + 2 < 16) LOADT((s + 2) * 64);
            const char* L = lds[s & 1];

            bf16x8 a[2][2];
            #pragma unroll
            for (int m = 0; m < 2; ++m) {
                const int arow = wr + m * 16 + lrow;
                #pragma unroll
                for (int kk = 0; kk < 2; ++kk)
                    a[m][kk] = *(const bf16x8*)(L +
                        ((arow * 128 + kk * 64 + lhi * 16) ^ ((arow & 7) << 4)));
            }
            #pragma unroll
            for (int n = 0; n < 4; ++n) {
                const int brow = wc + n * 16 + lrow;
                #pragma unroll
                for (int kk = 0; kk < 2; ++kk) {
                    bf16x8 b = *(const bf16x8*)(L + 8192 +
                        ((brow * 128 + kk * 64 + lhi * 16) ^ ((brow & 7) << 4)));
                    #pragma unroll
                    for (int m = 0; m < 2; ++m)
                        acc[m][n] = __builtin_amdgcn_mfma_f32_16x16x32_bf16(a[m][kk], b, acc[m][n], 0, 0, 0);
                }
            }
            __syncthreads();
        }

        #pragma unroll
        for (int m = 0; m < 2; ++m) {
            const int row0 = br * 64 + wr + m * 16 + lhi * 4;
            const int batch = row0 >> 12, tok = row0 & 4095;
            #pragma unroll
            for (int n = 0; n < 4; ++n) {
                int col = wc + n * 16 + lrow;
                float bv_ = bv[col];
                union { unsigned short s[4]; unsigned long long q; } pk;
                #pragma unroll
                for (int r = 0; r < 4; ++r) pk.s[r] = f2bf(acc[m][n][r] + bv_);
                *(unsigned long long*)&VpT[(size_t)batch * (LAT * NTOK) + (size_t)col * NTOK + tok] = pk.q;
            }
        }
    }
}

// ===========================================================================
// attn7<NSPLIT>: KVBLK=64, 4 waves x 32 q, 2-buffer gld_lds (pre-swizzled
// source), static max. Proven 54.4 us. Unchanged.
// ===========================================================================
template<int NSPLIT>
__global__ __launch_bounds__(256, 2) void attn7(const unsigned short* __restrict__ Qp,
                                                const unsigned short* __restrict__ Kp,
                                                const unsigned short* __restrict__ VpT,
                                                unsigned short* __restrict__ Opart,
                                                float* __restrict__ lsum,
                                                float* __restrict__ Y) {
    __shared__ __align__(16) char ldsK[2][16384];   // K [64 k][128 d] bf16
    __shared__ __align__(16) char ldsV[2][16384];   // VT [128 d][64 k] bf16
    const int t = threadIdx.x, l = t & 63, w = t >> 6;
    const int lane31 = l & 31, hi = l >> 5;

    int qt, b, ck;
    if constexpr (NSPLIT > 1) {
        int x = blockIdx.x;
        int glo = x & 7, rest = x >> 3;
        qt = rest & 31;
        int g = glo + 8 * (rest >> 5);   // 0 .. NB*NSPLIT-1
        b = g / NSPLIT; ck = g % NSPLIT;
    } else {
        qt = blockIdx.x & 31; b = blockIdx.x >> 5; ck = 0;
    }
    const size_t base  = (size_t)b * ((size_t)NTOK * LAT);
    const size_t vbase = (size_t)b * ((size_t)LAT * NTOK);
    const int wq = qt * 128 + w * 32;
    const int k_base = ck * (NTOK / NSPLIT);
    const int kts = (NTOK / NSPLIT) / 64;

    const int kc_row = t >> 4, kc_ch = t & 15;   // K: c=t+j*256 -> row=kc_row+j*16
    const int vc_row = t >> 3, vc_ch = t & 7;    // V: c=t+j*256 -> row=vc_row+j*32

    auto STAGE = [&](int bi, int k_lo) {
        #pragma unroll
        for (int j = 0; j < 4; ++j) {
            int row = kc_row + j * 16;
            gld16(&Kp[base + (size_t)(k_lo + row) * LAT + (kc_ch ^ (row & 15)) * 8],
                  &ldsK[bi][j * 4096 + w * 1024]);
        }
        #pragma unroll
        for (int j = 0; j < 4; ++j) {
            int row = vc_row + j * 32;
            gld16(&VpT[vbase + (size_t)row * NTOK + k_lo + (vc_ch ^ (row & 7)) * 8],
                  &ldsV[bi][j * 4096 + w * 1024]);
        }
    };

    bf16x8 qf[8];
    {
        const size_t qrow = base + (size_t)(wq + lane31) * LAT;
        #pragma unroll
        for (int ds = 0; ds < 8; ++ds)
            qf[ds] = *(const bf16x8*)&Qp[qrow + ds * 16 + hi * 8];
    }

    f32x16 OA[4] = {};
    float lrun = 0.f;

    int buf = 0;
    STAGE(0, k_base);
    asm volatile("s_waitcnt vmcnt(0)" ::: "memory");
    __syncthreads();

    for (int kt = 0; kt < kts; ++kt) {
        if (kt + 1 < kts) STAGE(buf ^ 1, k_base + (kt + 1) * 64);
        const char* lK = ldsK[buf];
        const char* lV = ldsV[buf];

        f32x16 SA[2];
        __builtin_amdgcn_s_setprio(1);
        #pragma unroll
        for (int kb = 0; kb < 2; ++kb) {
            f32x16 s = {};
            const int kr = kb * 32 + lane31;
            const int ksw = (kr & 15) << 4;
            #pragma unroll
            for (int ds = 0; ds < 8; ++ds) {
                bf16x8 kf = *(const bf16x8*)(lK + ((kr * 256 + ds * 32 + hi * 16) ^ ksw));
                s = __builtin_amdgcn_mfma_f32_32x32x16_bf16(kf, qf[ds], s, 0, 0, 0);
            }
            SA[kb] = s;
        }
        __builtin_amdgcn_s_setprio(0);

        #pragma unroll
        for (int kb = 0; kb < 2; ++kb) {
            float p[16];
            #pragma unroll
            for (int r = 0; r < 16; ++r) {
                p[r] = exp2f(SA[kb][r]);
                lrun += p[r];
            }
            unsigned a0 = cvtpk(p[0], p[1]),  a1 = cvtpk(p[2], p[3]);
            unsigned a2 = cvtpk(p[4], p[5]),  a3 = cvtpk(p[6], p[7]);
            permswap(a0, a2); permswap(a1, a3);
            unsigned b0 = cvtpk(p[8], p[9]),   b1 = cvtpk(p[10], p[11]);
            unsigned b2 = cvtpk(p[12], p[13]), b3 = cvtpk(p[14], p[15]);
            permswap(b0, b2); permswap(b1, b3);
            union { unsigned u[4]; bf16x8 v; } f0 = {{a0, a1, a2, a3}};
            union { unsigned u[4]; bf16x8 v; } f1 = {{b0, b1, b2, b3}};

            __builtin_amdgcn_s_setprio(1);
            #pragma unroll
            for (int db = 0; db < 4; ++db) {
                const int d = db * 32 + lane31;
                const int vsw = (d & 7) << 4;
                bf16x8 vfA = *(const bf16x8*)(lV + ((d * 128 + (kb * 2 + 0) * 32 + hi * 16) ^ vsw));
                OA[db] = __builtin_amdgcn_mfma_f32_32x32x16_bf16(vfA, f0.v, OA[db], 0, 0, 0);
                bf16x8 vfB = *(const bf16x8*)(lV + ((d * 128 + (kb * 2 + 1) * 32 + hi * 16) ^ vsw));
                OA[db] = __builtin_amdgcn_mfma_f32_32x32x16_bf16(vfB, f1.v, OA[db], 0, 0, 0);
            }
            __builtin_amdgcn_s_setprio(0);
        }

        asm volatile("s_waitcnt vmcnt(0)" ::: "memory");
        __syncthreads();
        buf ^= 1;
    }

    const float ltot = lrun + __shfl_xor(lrun, 32);

    if constexpr (NSPLIT == 1) {
        const float inv = 1.0f / ltot;
        float* dst = &Y[base + (size_t)(wq + lane31) * LAT];
        #pragma unroll
        for (int db = 0; db < 4; ++db)
            #pragma unroll
            for (int g = 0; g < 4; ++g) {
                f32x4 v;
                #pragma unroll
                for (int j = 0; j < 4; ++j) v[j] = OA[db][4 * g + j] * inv;
                *(f32x4*)&dst[db * 32 + 8 * g + 4 * hi] = v;
            }
    } else {
        const size_t prow = (size_t)ck * MTOT + (size_t)b * NTOK + wq + lane31;
        unsigned short* dst = &Opart[prow * LAT];
        #pragma unroll
        for (int db = 0; db < 4; ++db)
            #pragma unroll
            for (int g = 0; g < 4; ++g) {
                union { unsigned short s[4]; unsigned long long q; } pk;
                #pragma unroll
                for (int j = 0; j < 4; ++j) pk.s[j] = f2bf(OA[db][4 * g + j]);
                *(unsigned long long*)&dst[db * 32 + 8 * g + 4 * hi] = pk.q;
            }
        if (l < 32) lsum[prow] = ltot;
    }
}

// ===========================================================================
// merge3<S>: Y = (sum_c O_c) / (sum_c l_c).  (proven round 7)
// ===========================================================================
template<int S>
__global__ __launch_bounds__(256) void merge3(const unsigned short* __restrict__ Opart,
                                              const float* __restrict__ lsum,
                                              float* __restrict__ Y) {
    const int idx = blockIdx.x * 256 + threadIdx.x;
    const int row = idx >> 4, cc = (idx & 15) * 8;
    float L = 0.f;
    #pragma unroll
    for (int c = 0; c < S; ++c) L += lsum[(size_t)c * MTOT + row];
    float acc[8] = {};
    #pragma unroll
    for (int c = 0; c < S; ++c) {
        bf16x8 v = *(const bf16x8*)&Opart[((size_t)c * MTOT + row) * LAT + cc];
        #pragma unroll
        for (int j = 0; j < 8; ++j)
            acc[j] += bf2f((unsigned short)v[j]);
    }
    const float inv = 1.f / L;
    f32x4 o0, o1;
    #pragma unroll
    for (int j = 0; j < 4; ++j) { o0[j] = acc[j] * inv; o1[j] = acc[4 + j] * inv; }
    *(f32x4*)&Y[(size_t)row * LAT + cc] = o0;
    *(f32x4*)&Y[(size_t)row * LAT + cc + 4] = o1;
}

// ===========================================================================
extern "C" void kernel_launch(void* const* d_in, const int* in_sizes, int n_in,
                              void* d_out, int out_size, void* d_ws, size_t ws_size,
                              hipStream_t stream) {
    const float* Q  = (const float*)d_in[0];
    // d_in[1] (K) ignored by reference
    const float* V  = (const float*)d_in[2];
    const float* Wk = (const float*)d_in[3];
    const float* bk = (const float*)d_in[4];
    const float* Wq = (const float*)d_in[5];
    const float* bq = (const float*)d_in[6];
    const float* Wv = (const float*)d_in[7];
    const float* bv = (const float*)d_in[8];
    float* Y = (float*)d_out;

    char* ws = (char*)d_ws;
    unsigned short* Kp    = (unsigned short*)(ws);                 // 4 MB
    unsigned short* Qp    = (unsigned short*)(ws + (4 << 20));     // 4 MB
    unsigned short* VpT   = (unsigned short*)(ws + (8 << 20));     // 4 MB
    unsigned short* Wcomb = (unsigned short*)(ws + (12 << 20));    // 512 KB
    float*          bqk   = (float*)         (ws + 13107200);      // 512 B
    float*          lsum  = (float*)         (ws + 13107712);      // <=512 KB
    unsigned short* Opart = (unsigned short*)(ws + 14680064);      // partials
    const size_t need4 = 14680064 + (size_t)4 * MTOT * LAT * 2;    // ~31.5 MB

    fuse_w<<<dim3(4, 128), 256, 0, stream>>>(Wq, Wk, bk, bq, Wcomb, bqk);
    proj_all4<<<dim3(512), 256, 0, stream>>>(Q, Wcomb, bk, bqk, Kp, Qp, V, Wv, bv, VpT);

    if (ws_size >= need4) {
        attn7<4><<<dim3(32 * NB * 4), 256, 0, stream>>>(Qp, Kp, VpT, Opart, lsum, nullptr);
        merge3<4><<<dim3(MTOT * 16 / 256), 256, 0, stream>>>(Opart, lsum, Y);
    } else {
        attn7<1><<<dim3(32 * NB), 256, 0, stream>>>(Qp, Kp, VpT, nullptr, nullptr, Y);
    }
}